// Round 1
// baseline (496.626 us; speedup 1.0000x reference)
//
#include <hip/hip_runtime.h>

#define L_N 2500
#define B_N 1024
#define ROWSTRIDE 30000      // 12*2500, channel 0 only
#define NPATCH 50
#define PATCH 50

#define BM 80                // bins per block
#define BN 64                // batch rows per block
#define NKB 16               // 16*80 = 1280 bins computed (0..1250 used)
#define NBB 16               // 16*64 = 1024 rows
#define NCAND (NKB*3)        // 48 candidates per row

#define TWOPI_F 6.28318530717958647692f
#define TWOPI_D 6.283185307179586476925286766559

// ---------------- Kernel 0: exact f64 twiddle table ----------------
__global__ void make_tw64(double2* __restrict__ tw) {
    int i = blockIdx.x * blockDim.x + threadIdx.x;
    if (i < L_N) {
        double th = (double)i * (TWOPI_D / (double)L_N);
        tw[i] = make_double2(cos(th), sin(th));
    }
}

// ---- Kernel 1: fp32 DFT power + per-(row, kblock) top-3 candidate keys ----
// grid (NKB, NBB), block 256. Each thread: 5 bins x 4 batches.
__global__ __launch_bounds__(256, 1)
void dft_power_cand(const float* __restrict__ x, unsigned long long* __restrict__ cand) {
    __shared__ float buf[80 * 68];   // xs[t(64)][b(64)] stride 68, later pw[bin(80)][b(64)]
    const int tid = threadIdx.x;
    const int kb = blockIdx.x;
    const int bb = blockIdx.y;
    const int tx = tid & 15;         // batch group (4 batches)
    const int ty = tid >> 4;         // bin group (5 bins, strided by 16)
    const int b0 = bb * BN;
    const int k0 = kb * BM;

    int kbin[5];
    float stepc[5], steps[5];
#pragma unroll
    for (int i = 0; i < 5; ++i) {
        kbin[i] = k0 + ty + 16 * i;
        float th = (float)kbin[i] * (TWOPI_F / (float)L_N);
        __sincosf(th, &steps[i], &stepc[i]);   // per-t rotation step for bin k
    }
    float re[5][4], im[5][4];
#pragma unroll
    for (int i = 0; i < 5; ++i)
#pragma unroll
        for (int j = 0; j < 4; ++j) { re[i][j] = 0.f; im[i][j] = 0.f; }

    for (int tile = 0; tile < 40; ++tile) {      // 40*64 = 2560 >= 2500 (zero-padded)
        const int t0 = tile * 64;
        __syncthreads();
        // stage x[b0..b0+63][t0..t0+63] -> buf[t][b]
#pragma unroll
        for (int i = 0; i < 4; ++i) {
            int flat = tid + i * 256;            // 0..1023
            int bl = flat >> 4;                  // 0..63
            int tl = (flat & 15) * 4;            // 0..60
            int t = t0 + tl;
            float4 v = make_float4(0.f, 0.f, 0.f, 0.f);
            if (t < L_N)
                v = *reinterpret_cast<const float4*>(x + (size_t)(b0 + bl) * ROWSTRIDE + t);
            buf[(tl + 0) * 68 + bl] = v.x;
            buf[(tl + 1) * 68 + bl] = v.y;
            buf[(tl + 2) * 68 + bl] = v.z;
            buf[(tl + 3) * 68 + bl] = v.w;
        }
        __syncthreads();
        // exact reseed of (cos,sin)(2*pi*k*t0/L) per tile -> no drift accumulation
        float c[5], s[5];
#pragma unroll
        for (int i = 0; i < 5; ++i) {
            int ph = (kbin[i] * t0) % L_N;       // exact integer phase
            float th = (float)ph * (TWOPI_F / (float)L_N);
            __sincosf(th, &s[i], &c[i]);
        }
#pragma unroll 4
        for (int tt = 0; tt < 64; ++tt) {
            float4 xv = *reinterpret_cast<const float4*>(&buf[tt * 68 + tx * 4]);
#pragma unroll
            for (int i = 0; i < 5; ++i) {
                re[i][0] += xv.x * c[i]; im[i][0] += xv.x * s[i];
                re[i][1] += xv.y * c[i]; im[i][1] += xv.y * s[i];
                re[i][2] += xv.z * c[i]; im[i][2] += xv.z * s[i];
                re[i][3] += xv.w * c[i]; im[i][3] += xv.w * s[i];
                float cn = c[i] * stepc[i] - s[i] * steps[i];
                float sn = s[i] * stepc[i] + c[i] * steps[i];
                c[i] = cn; s[i] = sn;
            }
        }
    }
    __syncthreads();
    // powers -> buf[bin][batch]
#pragma unroll
    for (int i = 0; i < 5; ++i) {
        int kl = ty + 16 * i;
        float4 pv;
        pv.x = re[i][0] * re[i][0] + im[i][0] * im[i][0];
        pv.y = re[i][1] * re[i][1] + im[i][1] * im[i][1];
        pv.z = re[i][2] * re[i][2] + im[i][2] * im[i][2];
        pv.w = re[i][3] * re[i][3] + im[i][3] * im[i][3];
        *reinterpret_cast<float4*>(&buf[kl * 68 + tx * 4]) = pv;
    }
    __syncthreads();
    // per-batch top-3 over this block's 80 bins (k<=1250 only)
    if (tid < 64) {
        unsigned long long q0 = 0, q1 = 0, q2 = 0;
        for (int kl = 0; kl < BM; ++kl) {
            int kg = k0 + kl;
            if (kg > 1250) break;                // ascending -> safe
            float p = buf[kl * 68 + tid];
            // power >= 0 -> float bits monotonic; low word: smaller k wins ties
            unsigned long long key =
                ((unsigned long long)__float_as_uint(p) << 32) | (unsigned)(L_N - kg);
            if (key > q0)      { q2 = q1; q1 = q0; q0 = key; }
            else if (key > q1) { q2 = q1; q1 = key; }
            else if (key > q2) { q2 = key; }
        }
        unsigned long long* cp = cand + (size_t)(b0 + tid) * NCAND + kb * 3;
        cp[0] = q0; cp[1] = q1; cp[2] = q2;
    }
}

// ---- Kernel 2: f64 refine of top-8 candidates, rank, patch counts ----
// grid B_N, block 64 (one wave per row)
__global__ __launch_bounds__(64, 1)
void refine_topk_patches(const float* __restrict__ x, const double2* __restrict__ tw,
                         const unsigned long long* __restrict__ cand,
                         const float* __restrict__ wp, float* __restrict__ out) {
    __shared__ float xrow[L_N];
    const int row = blockIdx.x;
    const int lane = threadIdx.x;
    for (int t = lane; t < L_N; t += 64)
        xrow[t] = x[(size_t)row * ROWSTRIDE + t];
    __syncthreads();

    // top-8 distinct bins by fp32 key (48 distinct candidate keys)
    unsigned long long cur = (lane < NCAND) ? cand[(size_t)row * NCAND + lane] : 0ULL;
    int bins[8];
#pragma unroll
    for (int r = 0; r < 8; ++r) {
        unsigned long long v = cur;
#pragma unroll
        for (int off = 32; off > 0; off >>= 1) {
            unsigned long long o = __shfl_xor(v, off, 64);
            v = (o > v) ? o : v;
        }
        bins[r] = L_N - (int)(unsigned)(v & 0xffffffffULL);
        if (cur == v) cur = 0;
    }

    // exact-ish f64 power for each candidate bin, wave-parallel over t
    unsigned long long rq[8];
#pragma unroll
    for (int r = 0; r < 8; ++r) {
        const int k = bins[r];
        int idx = (k * lane) % L_N;
        const int step = (k * 64) % L_N;
        double re = 0.0, im = 0.0;
        for (int t = lane; t < L_N; t += 64) {
            double xv = (double)xrow[t];
            double2 w = tw[idx];
            re += xv * w.x;
            im += xv * w.y;
            idx += step; if (idx >= L_N) idx -= L_N;
        }
#pragma unroll
        for (int off = 32; off > 0; off >>= 1) {
            re += __shfl_xor(re, off, 64);
            im += __shfl_xor(im, off, 64);
        }
        double p = re * re + im * im;
        unsigned long long pb = (unsigned long long)__double_as_longlong(p);
        // clear 11 low mantissa bits (rel 2^-41) for the tie-break field: smaller k wins
        rq[r] = (pb & ~2047ULL) | (unsigned long long)(1250 - k);
    }

    // top-3 of the 8 refined keys (all lanes identical, fully unrolled)
    unsigned long long m1 = rq[0];
#pragma unroll
    for (int r = 1; r < 8; ++r) m1 = (rq[r] > m1) ? rq[r] : m1;
#pragma unroll
    for (int r = 0; r < 8; ++r) if (rq[r] == m1) rq[r] = 0;
    unsigned long long m2 = rq[0];
#pragma unroll
    for (int r = 1; r < 8; ++r) m2 = (rq[r] > m2) ? rq[r] : m2;
#pragma unroll
    for (int r = 0; r < 8; ++r) if (rq[r] == m2) rq[r] = 0;
    unsigned long long m3 = rq[0];
#pragma unroll
    for (int r = 1; r < 8; ++r) m3 = (rq[r] > m3) ? rq[r] : m3;

    int kA = 1250 - (int)(m1 & 2047ULL);
    int kB = 1250 - (int)(m2 & 2047ULL);
    int kC = 1250 - (int)(m3 & 2047ULL);
    // conjugate-pair multiplicity: ranks {0,2} of the full 2500-bin list
    int multA = (kA == 0 || kA == 1250) ? 1 : 2;
    int multB = (kB == 0 || kB == 1250) ? 1 : 2;
    int sel0 = kA;
    int sel1 = (multA == 2 || multB == 2) ? kB : kC;

    if (lane < NPATCH) {
        int start = lane * PATCH;
        int cnt = 0;
        if (sel0 != 0) {
            int p = L_N / sel0;
            int fm = ((start + p - 1) / p) * p;
            if (fm < start + PATCH) ++cnt;
        }
        if (sel1 != 0) {
            int p = L_N / sel1;
            int fm = ((start + p - 1) / p) * p;
            if (fm < start + PATCH) ++cnt;
        }
        out[(size_t)row * NPATCH + lane] = 12.0f * wp[0] * (float)cnt;
    }
}

extern "C" void kernel_launch(void* const* d_in, const int* in_sizes, int n_in,
                              void* d_out, int out_size, void* d_ws, size_t ws_size,
                              hipStream_t stream) {
    const float* x = (const float*)d_in[0];
    const float* w = (const float*)d_in[1];
    float* out = (float*)d_out;
    double2* tw = (double2*)d_ws;                                        // 40000 B
    unsigned long long* cand = (unsigned long long*)((char*)d_ws + 40960); // 393216 B

    make_tw64<<<10, 256, 0, stream>>>(tw);
    dim3 g(NKB, NBB);
    dft_power_cand<<<g, 256, 0, stream>>>(x, cand);
    refine_topk_patches<<<B_N, 64, 0, stream>>>(x, tw, cand, w, out);
}

// Round 2
// 424.770 us; speedup vs baseline: 1.1692x; 1.1692x over previous
//
#include <hip/hip_runtime.h>

#define L_N 2500
#define B_N 1024
#define ROWSTRIDE 30000      // 12*2500, channel 0 only
#define NPATCH 50
#define PATCH 50
#define NBINS 1280           // 16*80 bins computed, 0..1250 used
#define NKB 16
#define NBB 16

#define TWOPI_F 6.28318530717958647692f
#define TWOPI_D 6.283185307179586476925286766559

// ---------------- Kernel 0: exact f64 twiddle table ----------------
__global__ void make_tw64(double2* __restrict__ tw) {
    int i = blockIdx.x * blockDim.x + threadIdx.x;
    if (i < L_N) {
        double th = (double)i * (TWOPI_D / (double)L_N);
        tw[i] = make_double2(cos(th), sin(th));
    }
}

// ---- Kernel 1: fp32 DFT partial sums over a t-slice ----
// grid (16, 16, NS), block 256. Thread: 5 contiguous bins x 4 batches.
// part layout: part[(s*1024 + row)*NBINS + bin] = float2(re, im)
__global__ __launch_bounds__(256, 4)
void dft_power_part(const float* __restrict__ x, float2* __restrict__ part, int tps) {
    __shared__ float buf[64 * 68];   // xs[t(64)][b(64)] stride 68
    const int tid = threadIdx.x;
    const int kb = blockIdx.x;
    const int bb = blockIdx.y;
    const int sz = blockIdx.z;
    const int tx = tid & 15;         // batch group (4 batches)
    const int ty = tid >> 4;         // bin group (5 contiguous bins)
    const int b0 = bb * 64;
    const int k0 = kb * 80;

    int kbin[5];
    float stepc[5], steps[5];
#pragma unroll
    for (int i = 0; i < 5; ++i) {
        kbin[i] = k0 + ty * 5 + i;
        float th = (float)kbin[i] * (TWOPI_F / (float)L_N);
        __sincosf(th, &steps[i], &stepc[i]);   // per-t rotation step for bin k
    }
    float re[5][4], im[5][4];
#pragma unroll
    for (int i = 0; i < 5; ++i)
#pragma unroll
        for (int j = 0; j < 4; ++j) { re[i][j] = 0.f; im[i][j] = 0.f; }

    const int tile0 = sz * tps;
    for (int tile = tile0; tile < tile0 + tps; ++tile) {
        const int t0 = tile * 64;
        __syncthreads();
#pragma unroll
        for (int i = 0; i < 4; ++i) {
            int flat = tid + i * 256;            // 0..1023
            int bl = flat >> 4;                  // 0..63
            int tl = (flat & 15) * 4;            // 0..60
            int t = t0 + tl;
            float4 v = make_float4(0.f, 0.f, 0.f, 0.f);
            if (t < L_N)
                v = *reinterpret_cast<const float4*>(x + (size_t)(b0 + bl) * ROWSTRIDE + t);
            buf[(tl + 0) * 68 + bl] = v.x;
            buf[(tl + 1) * 68 + bl] = v.y;
            buf[(tl + 2) * 68 + bl] = v.z;
            buf[(tl + 3) * 68 + bl] = v.w;
        }
        __syncthreads();
        // exact reseed of (cos,sin)(2*pi*k*t0/L) per tile -> no drift accumulation
        float c[5], s[5];
#pragma unroll
        for (int i = 0; i < 5; ++i) {
            int ph = (kbin[i] * t0) % L_N;       // exact integer phase
            float th = (float)ph * (TWOPI_F / (float)L_N);
            __sincosf(th, &s[i], &c[i]);
        }
#pragma unroll 4
        for (int tt = 0; tt < 64; ++tt) {
            float4 xv = *reinterpret_cast<const float4*>(&buf[tt * 68 + tx * 4]);
#pragma unroll
            for (int i = 0; i < 5; ++i) {
                re[i][0] += xv.x * c[i]; im[i][0] += xv.x * s[i];
                re[i][1] += xv.y * c[i]; im[i][1] += xv.y * s[i];
                re[i][2] += xv.z * c[i]; im[i][2] += xv.z * s[i];
                re[i][3] += xv.w * c[i]; im[i][3] += xv.w * s[i];
                float cn = c[i] * stepc[i] - s[i] * steps[i];
                float sn = s[i] * stepc[i] + c[i] * steps[i];
                c[i] = cn; s[i] = sn;
            }
        }
    }
    // write partials: 5 contiguous bins -> 40B runs per (thread, batch)
#pragma unroll
    for (int j = 0; j < 4; ++j) {
        size_t base = ((size_t)(sz * B_N + b0 + tx * 4 + j)) * NBINS + k0 + ty * 5;
#pragma unroll
        for (int i = 0; i < 5; ++i)
            part[base + i] = make_float2(re[i][j], im[i][j]);
    }
}

// ---- Kernel 2: combine partials, exact top-8, f64 refine, patches ----
// grid B_N, block 256 (4 waves per row)
__global__ __launch_bounds__(256, 2)
void combine_refine(const float* __restrict__ x, const double2* __restrict__ tw,
                    const float2* __restrict__ part,
                    const float* __restrict__ wp, float* __restrict__ out, int ns) {
    __shared__ float xrow[L_N];
    __shared__ unsigned long long wred[4];
    __shared__ unsigned long long rk[8];
    const int row = blockIdx.x;
    const int tid = threadIdx.x;
    const int wv = tid >> 6;
    const int lane = tid & 63;

    for (int t = tid; t < L_N; t += 256)
        xrow[t] = x[(size_t)row * ROWSTRIDE + t];

    // combine splits -> power keys (5 bins/thread, coalesced reads)
    unsigned long long myk[5];
#pragma unroll
    for (int c = 0; c < 5; ++c) {
        int bin = tid + 256 * c;
        float re = 0.f, im = 0.f;
        for (int s = 0; s < ns; ++s) {
            float2 v = part[((size_t)(s * B_N + row)) * NBINS + bin];
            re += v.x; im += v.y;
        }
        float p = re * re + im * im;
        myk[c] = (bin <= 1250)
            ? (((unsigned long long)__float_as_uint(p) << 32) | (unsigned)(L_N - bin))
            : 0ULL;
    }

    // exact block-wide top-8 (fp32 key, smaller-k tiebreak)
    int bins8[8];
#pragma unroll
    for (int r = 0; r < 8; ++r) {
        unsigned long long m = myk[0];
#pragma unroll
        for (int c = 1; c < 5; ++c) m = (myk[c] > m) ? myk[c] : m;
#pragma unroll
        for (int off = 32; off > 0; off >>= 1) {
            unsigned long long o = __shfl_xor(m, off, 64);
            m = (o > m) ? o : m;
        }
        if (lane == 0) wred[wv] = m;
        __syncthreads();
        unsigned long long g = wred[0];
        g = (wred[1] > g) ? wred[1] : g;
        g = (wred[2] > g) ? wred[2] : g;
        g = (wred[3] > g) ? wred[3] : g;
#pragma unroll
        for (int c = 0; c < 5; ++c) if (myk[c] == g) myk[c] = 0ULL;
        bins8[r] = L_N - (int)(unsigned)(g & 0xffffffffULL);
        __syncthreads();     // protect wred before next round overwrites
    }

    // f64 refine: wave wv handles candidates 2wv, 2wv+1
#pragma unroll
    for (int q = 0; q < 2; ++q) {
        const int r = wv * 2 + q;
        const int k = bins8[r];
        int idx = (k * lane) % L_N;
        const int step = (k * 64) % L_N;
        double re = 0.0, im = 0.0;
        for (int t = lane; t < L_N; t += 64) {
            double xv = (double)xrow[t];
            double2 w = tw[idx];
            re += xv * w.x;
            im += xv * w.y;
            idx += step; if (idx >= L_N) idx -= L_N;
        }
#pragma unroll
        for (int off = 32; off > 0; off >>= 1) {
            re += __shfl_xor(re, off, 64);
            im += __shfl_xor(im, off, 64);
        }
        if (lane == 0) {
            double p = re * re + im * im;
            unsigned long long pb = (unsigned long long)__double_as_longlong(p);
            // clear 11 low mantissa bits (rel 2^-41); low field: smaller k wins
            rk[r] = (pb & ~2047ULL) | (unsigned long long)(1250 - k);
        }
    }
    __syncthreads();

    if (tid < NPATCH) {
        unsigned long long q[8];
#pragma unroll
        for (int r = 0; r < 8; ++r) q[r] = rk[r];
        unsigned long long m1 = q[0];
#pragma unroll
        for (int r = 1; r < 8; ++r) m1 = (q[r] > m1) ? q[r] : m1;
#pragma unroll
        for (int r = 0; r < 8; ++r) if (q[r] == m1) q[r] = 0;
        unsigned long long m2 = q[0];
#pragma unroll
        for (int r = 1; r < 8; ++r) m2 = (q[r] > m2) ? q[r] : m2;
#pragma unroll
        for (int r = 0; r < 8; ++r) if (q[r] == m2) q[r] = 0;
        unsigned long long m3 = q[0];
#pragma unroll
        for (int r = 1; r < 8; ++r) m3 = (q[r] > m3) ? q[r] : m3;

        int kA = 1250 - (int)(m1 & 2047ULL);
        int kB = 1250 - (int)(m2 & 2047ULL);
        int kC = 1250 - (int)(m3 & 2047ULL);
        int multA = (kA == 0 || kA == 1250) ? 1 : 2;
        int multB = (kB == 0 || kB == 1250) ? 1 : 2;
        int sel0 = kA;
        int sel1 = (multA == 2 || multB == 2) ? kB : kC;

        int start = tid * PATCH;
        int cnt = 0;
        if (sel0 != 0) {
            int p = L_N / sel0;
            int fm = ((start + p - 1) / p) * p;
            if (fm < start + PATCH) ++cnt;
        }
        if (sel1 != 0) {
            int p = L_N / sel1;
            int fm = ((start + p - 1) / p) * p;
            if (fm < start + PATCH) ++cnt;
        }
        out[(size_t)row * NPATCH + tid] = 12.0f * wp[0] * (float)cnt;
    }
}

extern "C" void kernel_launch(void* const* d_in, const int* in_sizes, int n_in,
                              void* d_out, int out_size, void* d_ws, size_t ws_size,
                              hipStream_t stream) {
    const float* x = (const float*)d_in[0];
    const float* w = (const float*)d_in[1];
    float* out = (float*)d_out;

    const size_t tw_bytes = 40960;
    const size_t per_split = (size_t)B_N * NBINS * sizeof(float2);  // 10,485,760 B

    int ns;  // deterministic: ws_size is fixed for the session
    if      (ws_size >= tw_bytes + 4 * per_split) ns = 4;
    else if (ws_size >= tw_bytes + 2 * per_split) ns = 2;
    else                                          ns = 1;
    const int tps = 40 / ns;

    double2* tw = (double2*)d_ws;
    float2* part = (float2*)((char*)d_ws + tw_bytes);

    make_tw64<<<10, 256, 0, stream>>>(tw);
    dim3 g(NKB, NBB, ns);
    dft_power_part<<<g, 256, 0, stream>>>(x, part, tps);
    combine_refine<<<B_N, 256, 0, stream>>>(x, tw, part, w, out, ns);
}

// Round 3
// 275.041 us; speedup vs baseline: 1.8056x; 1.5444x over previous
//
#include <hip/hip_runtime.h>

typedef _Float16 f16;
typedef _Float16 f16x8 __attribute__((ext_vector_type(8)));
typedef float f32x4 __attribute__((ext_vector_type(4)));

#define L_N 2500
#define B_N 1024
#define ROWSTRIDE 30000      // 12*2500, channel 0 only
#define NPATCH 50
#define PATCH 50
#define KP 2528              // K padded to 79*32
#define NB 2560              // 1280 bins * 2 (cos,sin) rows
#define TWOPI_F 6.28318530717958647692f
#define TWOPI_D 6.283185307179586476925286766559

// workspace layout (bytes); total ~33.9 MB < proven 41.98 MB
#define OFF_TW   0
#define OFF_XH   40960
#define SZ_X     (B_N * KP * 2)
#define OFF_XL   (OFF_XH + SZ_X)
#define OFF_W    (OFF_XL + SZ_X)
#define SZ_W     (NB * KP * 2)
#define OFF_C    (OFF_W + SZ_W)
#define SZ_C     (B_N * NB * 4)
#define OFF_CAND (OFF_C + SZ_C)

#define GLOAD16(gp, lp) __builtin_amdgcn_global_load_lds( \
    (const __attribute__((address_space(1))) unsigned int*)(gp), \
    (__attribute__((address_space(3))) unsigned int*)(lp), 16, 0, 0)

// ---------------- exact f64 twiddle table (for refine) ----------------
__global__ void make_tw64(double2* __restrict__ tw) {
    int i = blockIdx.x * blockDim.x + threadIdx.x;
    if (i < L_N) {
        double th = (double)i * (TWOPI_D / (double)L_N);
        tw[i] = make_double2(cos(th), sin(th));
    }
}

// ---------------- X -> f16 hi/lo split, K-padded ----------------
__global__ __launch_bounds__(256)
void gen_x(const float* __restrict__ x, f16* __restrict__ Xh, f16* __restrict__ Xl) {
    const int row = blockIdx.x, tid = threadIdx.x;
    for (int t = tid; t < KP; t += 256) {
        float v = (t < L_N) ? x[(size_t)row * ROWSTRIDE + t] : 0.f;
        f16 h = (f16)v;
        Xh[(size_t)row * KP + t] = h;
        Xl[(size_t)row * KP + t] = (f16)(v - (float)h);
    }
}

// ---------------- W twiddle rows (f16): row 2k = cos, 2k+1 = sin ----------------
__global__ __launch_bounds__(256)
void gen_w(f16* __restrict__ W) {
    const int bin = blockIdx.x;          // 0..1279
    const int tid = threadIdx.x;
    for (int t = tid; t < KP; t += 256) {
        float c = 0.f, s = 0.f;
        if (t < L_N) {
            int ph = (bin * t) % L_N;    // exact integer phase (compiler magic-div)
            float th = (float)ph * (TWOPI_F / (float)L_N);
            __sincosf(th, &s, &c);
        }
        W[(size_t)(2 * bin) * KP + t]     = (f16)c;
        W[(size_t)(2 * bin + 1) * KP + t] = (f16)s;
    }
}

__global__ void zero_c(float4* __restrict__ C) {
    int i = blockIdx.x * blockDim.x + threadIdx.x;   // grid sized exactly SZ_C/16
    C[i] = make_float4(0.f, 0.f, 0.f, 0.f);
}

// ---------------- f16 MFMA GEMM: C[1024][2560] += A·W^T ----------------
// grid (8, 20, 4): z = pass(Xh/Xl) | K-half. 128x128 tile, BK=32, 4 waves (2x2 of 64x64).
__global__ __launch_bounds__(256)
void gemm_f16(const f16* __restrict__ Xh, const f16* __restrict__ Xl,
              const f16* __restrict__ W, float* __restrict__ C) {
    __shared__ f16 As[128 * 32];
    __shared__ f16 Bs[128 * 32];
    const int tid = threadIdx.x;
    const int wv = tid >> 6, lane = tid & 63;
    const int bm = blockIdx.x, bn = blockIdx.y;
    const int pass = blockIdx.z & 1, half = blockIdx.z >> 1;
    const f16* A = pass ? Xl : Xh;
    const int ks0 = half ? 40 : 0;
    const int ksn = half ? 39 : 40;
    const int wr = wv >> 1, wc = wv & 1;
    const int lrow = lane & 15, lk = (lane >> 4) * 8;

    f32x4 acc[4][4];
#pragma unroll
    for (int m = 0; m < 4; ++m)
#pragma unroll
        for (int n = 0; n < 4; ++n) acc[m][n] = (f32x4){0.f, 0.f, 0.f, 0.f};

    // staging chunks: chunk c -> row c>>2, k-seg c&3 (8 f16 = 16B)
    const int c0 = wv * 128 + lane, c1 = c0 + 64;
    const f16* ga0 = A + (size_t)(bm * 128 + (c0 >> 2)) * KP + (c0 & 3) * 8;
    const f16* ga1 = A + (size_t)(bm * 128 + (c1 >> 2)) * KP + (c1 & 3) * 8;
    const f16* gb0 = W + (size_t)(bn * 128 + (c0 >> 2)) * KP + (c0 & 3) * 8;
    const f16* gb1 = W + (size_t)(bn * 128 + (c1 >> 2)) * KP + (c1 & 3) * 8;

    for (int ks = ks0; ks < ks0 + ksn; ++ks) {
        const int kof = ks * 32;
        __syncthreads();                       // prior reads done before overwrite
        GLOAD16(ga0 + kof, &As[(wv * 128) * 8]);
        GLOAD16(ga1 + kof, &As[(wv * 128 + 64) * 8]);
        GLOAD16(gb0 + kof, &Bs[(wv * 128) * 8]);
        GLOAD16(gb1 + kof, &Bs[(wv * 128 + 64) * 8]);
        __syncthreads();                       // compiler drains vmcnt before barrier
        f16x8 af[4], bf[4];
#pragma unroll
        for (int m = 0; m < 4; ++m)
            af[m] = *(const f16x8*)&As[(wr * 64 + m * 16 + lrow) * 32 + lk];
#pragma unroll
        for (int n = 0; n < 4; ++n)
            bf[n] = *(const f16x8*)&Bs[(wc * 64 + n * 16 + lrow) * 32 + lk];
#pragma unroll
        for (int m = 0; m < 4; ++m)
#pragma unroll
            for (int n = 0; n < 4; ++n)
                acc[m][n] = __builtin_amdgcn_mfma_f32_16x16x32_f16(af[m], bf[n], acc[m][n], 0, 0, 0);
    }
    // epilogue: accumulate across z via fp32 atomics (C zero-initialized)
    const int orow0 = bm * 128 + wr * 64 + (lane >> 4) * 4;
    const int ocol0 = bn * 128 + wc * 64 + (lane & 15);
#pragma unroll
    for (int m = 0; m < 4; ++m)
#pragma unroll
        for (int n = 0; n < 4; ++n)
#pragma unroll
            for (int j = 0; j < 4; ++j)
                atomicAdd(&C[(size_t)(orow0 + m * 16 + j) * NB + ocol0 + n * 16], acc[m][n][j]);
}

// ---------------- per-row exact top-8 candidate bins from C ----------------
__global__ __launch_bounds__(256)
void top8_sel(const float* __restrict__ C, int* __restrict__ cand) {
    __shared__ unsigned long long wred[4];
    const int row = blockIdx.x, tid = threadIdx.x;
    const int wv = tid >> 6, lane = tid & 63;
    unsigned long long myk[5];
#pragma unroll
    for (int c = 0; c < 5; ++c) {
        int bin = tid + 256 * c;
        unsigned long long key = 0ULL;
        if (bin <= 1250) {
            float re = C[(size_t)row * NB + 2 * bin];
            float im = C[(size_t)row * NB + 2 * bin + 1];
            float p = re * re + im * im;
            key = ((unsigned long long)__float_as_uint(p) << 32) | (unsigned)(L_N - bin);
        }
        myk[c] = key;
    }
    int bins8[8];
#pragma unroll
    for (int r = 0; r < 8; ++r) {
        unsigned long long m = myk[0];
#pragma unroll
        for (int c = 1; c < 5; ++c) m = (myk[c] > m) ? myk[c] : m;
#pragma unroll
        for (int off = 32; off > 0; off >>= 1) {
            unsigned long long o = __shfl_xor(m, off, 64);
            m = (o > m) ? o : m;
        }
        if (lane == 0) wred[wv] = m;
        __syncthreads();
        unsigned long long g = wred[0];
        g = (wred[1] > g) ? wred[1] : g;
        g = (wred[2] > g) ? wred[2] : g;
        g = (wred[3] > g) ? wred[3] : g;
#pragma unroll
        for (int c = 0; c < 5; ++c) if (myk[c] == g) myk[c] = 0ULL;
        bins8[r] = L_N - (int)(unsigned)(g & 0xffffffffULL);
        __syncthreads();
    }
    if (tid == 0) {
#pragma unroll
        for (int r = 0; r < 8; ++r) cand[row * 8 + r] = bins8[r];
    }
}

// ---------------- f64 refine (1 cand/wave), rank, patch counts ----------------
__global__ __launch_bounds__(512)
void refine_patches(const float* __restrict__ x, const double2* __restrict__ tw,
                    const int* __restrict__ cand, const float* __restrict__ wp,
                    float* __restrict__ out) {
    __shared__ float xrow[L_N];
    __shared__ unsigned long long rk[8];
    const int row = blockIdx.x, tid = threadIdx.x;
    const int wv = tid >> 6, lane = tid & 63;
    for (int t = tid; t < L_N; t += 512)
        xrow[t] = x[(size_t)row * ROWSTRIDE + t];
    const int k = cand[row * 8 + wv];
    __syncthreads();

    int idx = (k * lane) % L_N;
    const int step = (k * 64) % L_N;
    double re = 0.0, im = 0.0;
    for (int t = lane; t < L_N; t += 64) {
        double xv = (double)xrow[t];
        double2 w = tw[idx];
        re += xv * w.x;
        im += xv * w.y;
        idx += step; if (idx >= L_N) idx -= L_N;
    }
#pragma unroll
    for (int off = 32; off > 0; off >>= 1) {
        re += __shfl_xor(re, off, 64);
        im += __shfl_xor(im, off, 64);
    }
    if (lane == 0) {
        double p = re * re + im * im;
        unsigned long long pb = (unsigned long long)__double_as_longlong(p);
        rk[wv] = (pb & ~2047ULL) | (unsigned long long)(1250 - k);
    }
    __syncthreads();

    if (tid < NPATCH) {
        unsigned long long q[8];
#pragma unroll
        for (int r = 0; r < 8; ++r) q[r] = rk[r];
        unsigned long long m1 = q[0];
#pragma unroll
        for (int r = 1; r < 8; ++r) m1 = (q[r] > m1) ? q[r] : m1;
#pragma unroll
        for (int r = 0; r < 8; ++r) if (q[r] == m1) q[r] = 0;
        unsigned long long m2 = q[0];
#pragma unroll
        for (int r = 1; r < 8; ++r) m2 = (q[r] > m2) ? q[r] : m2;
#pragma unroll
        for (int r = 0; r < 8; ++r) if (q[r] == m2) q[r] = 0;
        unsigned long long m3 = q[0];
#pragma unroll
        for (int r = 1; r < 8; ++r) m3 = (q[r] > m3) ? q[r] : m3;

        int kA = 1250 - (int)(m1 & 2047ULL);
        int kB = 1250 - (int)(m2 & 2047ULL);
        int kC = 1250 - (int)(m3 & 2047ULL);
        int multA = (kA == 0 || kA == 1250) ? 1 : 2;
        int multB = (kB == 0 || kB == 1250) ? 1 : 2;
        int sel0 = kA;
        int sel1 = (multA == 2 || multB == 2) ? kB : kC;

        int start = tid * PATCH;
        int cnt = 0;
        if (sel0 != 0) {
            int p = L_N / sel0;
            int fm = ((start + p - 1) / p) * p;
            if (fm < start + PATCH) ++cnt;
        }
        if (sel1 != 0) {
            int p = L_N / sel1;
            int fm = ((start + p - 1) / p) * p;
            if (fm < start + PATCH) ++cnt;
        }
        out[(size_t)row * NPATCH + tid] = 12.0f * wp[0] * (float)cnt;
    }
}

extern "C" void kernel_launch(void* const* d_in, const int* in_sizes, int n_in,
                              void* d_out, int out_size, void* d_ws, size_t ws_size,
                              hipStream_t stream) {
    const float* x = (const float*)d_in[0];
    const float* w = (const float*)d_in[1];
    float* out = (float*)d_out;
    char* ws = (char*)d_ws;

    double2* tw = (double2*)(ws + OFF_TW);
    f16* Xh = (f16*)(ws + OFF_XH);
    f16* Xl = (f16*)(ws + OFF_XL);
    f16* W  = (f16*)(ws + OFF_W);
    float* C = (float*)(ws + OFF_C);
    int* cand = (int*)(ws + OFF_CAND);

    make_tw64<<<10, 256, 0, stream>>>(tw);
    gen_x<<<B_N, 256, 0, stream>>>(x, Xh, Xl);
    gen_w<<<1280, 256, 0, stream>>>(W);
    zero_c<<<SZ_C / 16 / 256, 256, 0, stream>>>((float4*)C);
    gemm_f16<<<dim3(8, 20, 4), 256, 0, stream>>>(Xh, Xl, W, C);
    top8_sel<<<B_N, 256, 0, stream>>>(C, cand);
    refine_patches<<<B_N, 512, 0, stream>>>(x, tw, cand, w, out);
}

// Round 4
// 235.501 us; speedup vs baseline: 2.1088x; 1.1679x over previous
//
#include <hip/hip_runtime.h>

typedef _Float16 f16;
typedef _Float16 f16x4 __attribute__((ext_vector_type(4)));
typedef _Float16 f16x8 __attribute__((ext_vector_type(8)));
typedef float f32x4 __attribute__((ext_vector_type(4)));

#define L_N 2500
#define B_N 1024
#define ROWSTRIDE 30000      // 12*2500, channel 0 only
#define NPATCH 50
#define PATCH 50
#define KP 2560              // K padded to 80*32 (pad region zeroed)
#define NB 2560              // 1280 bins * 2 (cos,sin) rows
#define ZSPLIT 4
#define KS_PER_Z 20          // 80 K-steps / 4

#define TWOPI_F 6.28318530717958647692f
#define RAD_PER_PH (6.283185307179586476925286766559 / 2500.0)

// workspace layout (bytes); total ~27.5 MB (proven budget >= 42 MB from R2)
#define OFF_XH 0
#define SZ_XH (B_N * KP * 2)          // 5,242,880
#define OFF_W  (OFF_XH + SZ_XH)
#define SZ_W   (NB * KP * 2)          // 13,107,200
#define OFF_C  (OFF_W + SZ_W)
#define SZ_C   (B_N * NB * 4)         // 10,485,760

#define GLOAD16(gp, lp) __builtin_amdgcn_global_load_lds( \
    (const __attribute__((address_space(1))) unsigned int*)(gp), \
    (__attribute__((address_space(3))) unsigned int*)(lp), 16, 0, 0)

// ---------------- X -> f16 (single precision level), K-padded ----------------
__global__ __launch_bounds__(256)
void gen_x(const float* __restrict__ x, f16* __restrict__ Xh) {
    const int row = blockIdx.x, tid = threadIdx.x;
#pragma unroll
    for (int i = 0; i < 3; ++i) {
        int slot = tid + 256 * i;                 // float4 slot, 640 per row
        if (slot < 640) {
            float4 v = make_float4(0.f, 0.f, 0.f, 0.f);
            if (slot < 625)                       // 2500/4 == 625 exactly
                v = *reinterpret_cast<const float4*>(x + (size_t)row * ROWSTRIDE + slot * 4);
            f16x4 h = { (f16)v.x, (f16)v.y, (f16)v.z, (f16)v.w };
            *reinterpret_cast<f16x4*>(Xh + (size_t)row * KP + slot * 4) = h;
        }
    }
}

// ---------------- W twiddle rows (f16): row 2k = cos, 2k+1 = sin ----------------
__global__ __launch_bounds__(256)
void gen_w(f16* __restrict__ W) {
    const int bin = blockIdx.x;          // 0..1279
    const int tid = threadIdx.x;
    for (int t = tid; t < KP; t += 256) {
        float c = 0.f, s = 0.f;
        if (t < L_N) {
            int ph = (bin * t) % L_N;    // exact integer phase
            float th = (float)ph * (TWOPI_F / (float)L_N);
            __sincosf(th, &s, &c);
        }
        W[(size_t)(2 * bin) * KP + t]     = (f16)c;
        W[(size_t)(2 * bin + 1) * KP + t] = (f16)s;
    }
}

__global__ void zero_c(float4* __restrict__ C) {
    int i = blockIdx.x * blockDim.x + threadIdx.x;   // grid sized exactly SZ_C/16
    C[i] = make_float4(0.f, 0.f, 0.f, 0.f);
}

// ---------------- f16 MFMA GEMM: C[1024][2560] += Xh·W^T (z = K-quarter) ----------------
// grid (8, 20, 4), 128x128 tile, BK=32, 4 waves (2x2 of 64x64).
// LDS seg-swizzle: slot (r, q) holds global seg q ^ ((r>>1)&3)  (2-way banks on read = free)
__global__ __launch_bounds__(256)
void gemm_f16(const f16* __restrict__ A, const f16* __restrict__ W, float* __restrict__ C) {
    __shared__ f16 As[128 * 32];
    __shared__ f16 Bs[128 * 32];
    const int tid = threadIdx.x;
    const int wv = tid >> 6, lane = tid & 63;
    const int bm = blockIdx.x, bn = blockIdx.y;
    const int ks0 = blockIdx.z * KS_PER_Z;
    const int wr = wv >> 1, wc = wv & 1;
    const int lrow = lane & 15, lseg = lane >> 4;

    f32x4 acc[4][4];
#pragma unroll
    for (int m = 0; m < 4; ++m)
#pragma unroll
        for (int n = 0; n < 4; ++n) acc[m][n] = (f32x4){0.f, 0.f, 0.f, 0.f};

    // staging chunks: chunk c -> LDS slot (R=c>>2, S=c&3); global seg inverse-swizzled
    const int c0 = wv * 128 + lane, c1 = c0 + 64;
    const int R0 = c0 >> 2, S0 = (c0 & 3) ^ ((R0 >> 1) & 3);
    const int R1 = c1 >> 2, S1 = (c1 & 3) ^ ((R1 >> 1) & 3);
    const f16* ga0 = A + (size_t)(bm * 128 + R0) * KP + S0 * 8;
    const f16* ga1 = A + (size_t)(bm * 128 + R1) * KP + S1 * 8;
    const f16* gb0 = W + (size_t)(bn * 128 + R0) * KP + S0 * 8;
    const f16* gb1 = W + (size_t)(bn * 128 + R1) * KP + S1 * 8;

    // K-invariant swizzled LDS read offsets (f16 elem units)
    int aoff[4], boff[4];
#pragma unroll
    for (int m = 0; m < 4; ++m) {
        int ra = wr * 64 + m * 16 + lrow;
        aoff[m] = ra * 32 + ((lseg ^ ((ra >> 1) & 3)) * 8);
        int rb = wc * 64 + m * 16 + lrow;
        boff[m] = rb * 32 + ((lseg ^ ((rb >> 1) & 3)) * 8);
    }

    for (int ks = ks0; ks < ks0 + KS_PER_Z; ++ks) {
        const int kof = ks * 32;
        __syncthreads();                       // prior reads done before overwrite
        GLOAD16(ga0 + kof, &As[c0 * 8]);
        GLOAD16(ga1 + kof, &As[c1 * 8]);
        GLOAD16(gb0 + kof, &Bs[c0 * 8]);
        GLOAD16(gb1 + kof, &Bs[c1 * 8]);
        __syncthreads();                       // compiler drains vmcnt before barrier
        f16x8 af[4], bf[4];
#pragma unroll
        for (int m = 0; m < 4; ++m) af[m] = *(const f16x8*)&As[aoff[m]];
#pragma unroll
        for (int n = 0; n < 4; ++n) bf[n] = *(const f16x8*)&Bs[boff[n]];
#pragma unroll
        for (int m = 0; m < 4; ++m)
#pragma unroll
            for (int n = 0; n < 4; ++n)
                acc[m][n] = __builtin_amdgcn_mfma_f32_16x16x32_f16(af[m], bf[n], acc[m][n], 0, 0, 0);
    }
    // epilogue: accumulate across z via fp32 atomics (C zero-initialized)
    const int orow0 = bm * 128 + wr * 64 + (lane >> 4) * 4;
    const int ocol0 = bn * 128 + wc * 64 + (lane & 15);
#pragma unroll
    for (int m = 0; m < 4; ++m)
#pragma unroll
        for (int n = 0; n < 4; ++n)
#pragma unroll
            for (int j = 0; j < 4; ++j)
                atomicAdd(&C[(size_t)(orow0 + m * 16 + j) * NB + ocol0 + n * 16], acc[m][n][j]);
}

// ---- fused: per-row top-8 (exact on fp32 keys) + f64 rotation refine + patches ----
// grid B_N, block 512 (8 waves; 1 candidate per wave)
__global__ __launch_bounds__(512)
void fused_sel(const float* __restrict__ x, const float* __restrict__ C,
               const float* __restrict__ wp, float* __restrict__ out) {
    __shared__ float xrow[KP];
    __shared__ unsigned long long keybuf[64];
    __shared__ int bins8s[8];
    __shared__ unsigned long long rk[8];
    const int row = blockIdx.x, tid = threadIdx.x;
    const int wv = tid >> 6, lane = tid & 63;

    for (int t = tid; t < KP; t += 512)
        xrow[t] = (t < L_N) ? x[(size_t)row * ROWSTRIDE + t] : 0.f;

    // power keys: thread covers bins {tid, tid+512, tid+1024}
    unsigned long long k3[3];
#pragma unroll
    for (int c = 0; c < 3; ++c) {
        int bin = tid + 512 * c;
        unsigned long long key = 0ULL;
        if (bin <= 1250) {
            float re = C[(size_t)row * NB + 2 * bin];
            float im = C[(size_t)row * NB + 2 * bin + 1];
            float p = re * re + im * im;
            key = ((unsigned long long)__float_as_uint(p) << 32) | (unsigned)(L_N - bin);
        }
        k3[c] = key;
    }
    // wave-local top-8 (no barriers)
#pragma unroll
    for (int r = 0; r < 8; ++r) {
        unsigned long long m = k3[0];
        m = (k3[1] > m) ? k3[1] : m;
        m = (k3[2] > m) ? k3[2] : m;
#pragma unroll
        for (int off = 32; off > 0; off >>= 1) {
            unsigned long long o = __shfl_xor(m, off, 64);
            m = (o > m) ? o : m;
        }
        if (k3[0] == m) k3[0] = 0ULL;
        if (k3[1] == m) k3[1] = 0ULL;
        if (k3[2] == m) k3[2] = 0ULL;
        if (lane == 0) keybuf[wv * 8 + r] = m;
    }
    __syncthreads();
    // merge 8x8 wave-top8s in wave 0
    if (wv == 0) {
        unsigned long long cur = keybuf[lane];
#pragma unroll
        for (int r = 0; r < 8; ++r) {
            unsigned long long m = cur;
#pragma unroll
            for (int off = 32; off > 0; off >>= 1) {
                unsigned long long o = __shfl_xor(m, off, 64);
                m = (o > m) ? o : m;
            }
            if (cur == m) cur = 0ULL;
            if (lane == 0) bins8s[r] = L_N - (int)(unsigned)(m & 0xffffffffULL);
        }
    }
    __syncthreads();

    // f64 refine of candidate wv: sincos seed + 40-step in-register rotation
    const int k = bins8s[wv];
    double c, s, cd, sd;
    {
        int ph0 = (k * lane) % L_N;
        int phd = (k * 64) % L_N;
        sincos((double)ph0 * RAD_PER_PH, &s, &c);
        sincos((double)phd * RAD_PER_PH, &sd, &cd);
    }
    double re = 0.0, im = 0.0;
#pragma unroll 4
    for (int i = 0; i < 40; ++i) {            // 40*64 == 2560 == KP exactly
        double xv = (double)xrow[lane + 64 * i];
        re += xv * c;
        im += xv * s;
        double cn = c * cd - s * sd;
        double sn = s * cd + c * sd;
        c = cn; s = sn;
    }
#pragma unroll
    for (int off = 32; off > 0; off >>= 1) {
        re += __shfl_xor(re, off, 64);
        im += __shfl_xor(im, off, 64);
    }
    if (lane == 0) {
        double p = re * re + im * im;
        unsigned long long pb = (unsigned long long)__double_as_longlong(p);
        // clear 11 low mantissa bits (rel 2^-41); low field: smaller k wins ties
        rk[wv] = (pb & ~2047ULL) | (unsigned long long)(1250 - k);
    }
    __syncthreads();

    if (tid < NPATCH) {
        unsigned long long q[8];
#pragma unroll
        for (int r = 0; r < 8; ++r) q[r] = rk[r];
        unsigned long long m1 = q[0];
#pragma unroll
        for (int r = 1; r < 8; ++r) m1 = (q[r] > m1) ? q[r] : m1;
#pragma unroll
        for (int r = 0; r < 8; ++r) if (q[r] == m1) q[r] = 0;
        unsigned long long m2 = q[0];
#pragma unroll
        for (int r = 1; r < 8; ++r) m2 = (q[r] > m2) ? q[r] : m2;
#pragma unroll
        for (int r = 0; r < 8; ++r) if (q[r] == m2) q[r] = 0;
        unsigned long long m3 = q[0];
#pragma unroll
        for (int r = 1; r < 8; ++r) m3 = (q[r] > m3) ? q[r] : m3;

        int kA = 1250 - (int)(m1 & 2047ULL);
        int kB = 1250 - (int)(m2 & 2047ULL);
        int kC = 1250 - (int)(m3 & 2047ULL);
        int multA = (kA == 0 || kA == 1250) ? 1 : 2;
        int multB = (kB == 0 || kB == 1250) ? 1 : 2;
        int sel0 = kA;
        int sel1 = (multA == 2 || multB == 2) ? kB : kC;

        int start = tid * PATCH;
        int cnt = 0;
        if (sel0 != 0) {
            int p = L_N / sel0;
            int fm = ((start + p - 1) / p) * p;
            if (fm < start + PATCH) ++cnt;
        }
        if (sel1 != 0) {
            int p = L_N / sel1;
            int fm = ((start + p - 1) / p) * p;
            if (fm < start + PATCH) ++cnt;
        }
        out[(size_t)row * NPATCH + tid] = 12.0f * wp[0] * (float)cnt;
    }
}

extern "C" void kernel_launch(void* const* d_in, const int* in_sizes, int n_in,
                              void* d_out, int out_size, void* d_ws, size_t ws_size,
                              hipStream_t stream) {
    const float* x = (const float*)d_in[0];
    const float* w = (const float*)d_in[1];
    float* out = (float*)d_out;
    char* ws = (char*)d_ws;

    f16* Xh = (f16*)(ws + OFF_XH);
    f16* W  = (f16*)(ws + OFF_W);
    float* C = (float*)(ws + OFF_C);

    gen_x<<<B_N, 256, 0, stream>>>(x, Xh);
    gen_w<<<1280, 256, 0, stream>>>(W);
    zero_c<<<SZ_C / 16 / 256, 256, 0, stream>>>((float4*)C);
    gemm_f16<<<dim3(8, 20, ZSPLIT), 256, 0, stream>>>(Xh, W, C);
    fused_sel<<<B_N, 512, 0, stream>>>(x, C, w, out);
}

// Round 5
// 228.495 us; speedup vs baseline: 2.1735x; 1.0307x over previous
//
#include <hip/hip_runtime.h>

typedef _Float16 f16;
typedef _Float16 f16x4 __attribute__((ext_vector_type(4)));
typedef _Float16 f16x8 __attribute__((ext_vector_type(8)));
typedef float f32x4 __attribute__((ext_vector_type(4)));

#define L_N 2500
#define B_N 1024
#define ROWSTRIDE 30000      // 12*2500, channel 0 only
#define NPATCH 50
#define PATCH 50
#define KP 2560              // K padded to 80*32 (pad region zeroed)
#define NB 2560              // 1280 bins * 2 (cos,sin) rows
#define ZSPLIT 4
#define KS_PER_Z 20          // 80 K-steps / 4

#define TWOPI_F 6.28318530717958647692f
#define RAD_PER_PH (6.283185307179586476925286766559 / 2500.0)

// workspace layout (bytes); total ~27.5 MB
#define OFF_XH 0
#define SZ_XH (B_N * KP * 2)          // 5,242,880
#define OFF_W  (OFF_XH + SZ_XH)
#define SZ_W   (NB * KP * 2)          // 13,107,200
#define OFF_C  (OFF_W + SZ_W)
#define SZ_C   (B_N * NB * 4)         // 10,485,760

// prep-kernel block ranges
#define PB_X    B_N                    // 1024 blocks: x -> f16
#define PB_W    1280                   // 1280 blocks: twiddles
#define PB_Z    (SZ_C / 16 / 256)      // 2560 blocks: zero C
#define PB_TOT  (PB_X + PB_W + PB_Z)   // 4864

#define GLOAD16(gp, lp) __builtin_amdgcn_global_load_lds( \
    (const __attribute__((address_space(1))) unsigned int*)(gp), \
    (__attribute__((address_space(3))) unsigned int*)(lp), 16, 0, 0)

// ------- fused prep: gen_x | gen_w | zero_c by blockIdx range -------
__global__ __launch_bounds__(256)
void prep(const float* __restrict__ x, f16* __restrict__ Xh,
          f16* __restrict__ W, float4* __restrict__ C4) {
    const int b = blockIdx.x, tid = threadIdx.x;
    if (b < PB_X) {
        const int row = b;
#pragma unroll
        for (int i = 0; i < 3; ++i) {
            int slot = tid + 256 * i;                 // float4 slot, 640 per row
            if (slot < 640) {
                float4 v = make_float4(0.f, 0.f, 0.f, 0.f);
                if (slot < 625)                       // 2500/4 == 625 exactly
                    v = *reinterpret_cast<const float4*>(x + (size_t)row * ROWSTRIDE + slot * 4);
                f16x4 h = { (f16)v.x, (f16)v.y, (f16)v.z, (f16)v.w };
                *reinterpret_cast<f16x4*>(Xh + (size_t)row * KP + slot * 4) = h;
            }
        }
    } else if (b < PB_X + PB_W) {
        const int bin = b - PB_X;                     // 0..1279
        for (int t = tid; t < KP; t += 256) {
            float c = 0.f, s = 0.f;
            if (t < L_N) {
                int ph = (bin * t) % L_N;             // exact integer phase
                float th = (float)ph * (TWOPI_F / (float)L_N);
                __sincosf(th, &s, &c);
            }
            W[(size_t)(2 * bin) * KP + t]     = (f16)c;
            W[(size_t)(2 * bin + 1) * KP + t] = (f16)s;
        }
    } else {
        int i = (b - PB_X - PB_W) * 256 + tid;        // exact: PB_Z*256 slots
        C4[i] = make_float4(0.f, 0.f, 0.f, 0.f);
    }
}

// ------- f16 MFMA GEMM, 2-phase LDS double-buffer (T3-min recipe) -------
// grid (8, 20, 4): z = K-quarter. 128x128 tile, BK=32, 4 waves (2x2 of 64x64).
// LDS seg-swizzle (validated R4): slot (r,q) holds global seg q ^ ((r>>1)&3)
__global__ __launch_bounds__(256)
void gemm_f16(const f16* __restrict__ A, const f16* __restrict__ W, float* __restrict__ C) {
    __shared__ f16 As[2][128 * 32];
    __shared__ f16 Bs[2][128 * 32];
    const int tid = threadIdx.x;
    const int wv = tid >> 6, lane = tid & 63;
    const int bm = blockIdx.x, bn = blockIdx.y;
    const int ks0 = blockIdx.z * KS_PER_Z;
    const int wr = wv >> 1, wc = wv & 1;
    const int lrow = lane & 15, lseg = lane >> 4;

    f32x4 acc[4][4];
#pragma unroll
    for (int m = 0; m < 4; ++m)
#pragma unroll
        for (int n = 0; n < 4; ++n) acc[m][n] = (f32x4){0.f, 0.f, 0.f, 0.f};

    // staging chunks: chunk c -> LDS slot (R=c>>2, S=c&3); global seg inverse-swizzled
    const int c0 = wv * 128 + lane, c1 = c0 + 64;
    const int R0 = c0 >> 2, S0 = (c0 & 3) ^ ((R0 >> 1) & 3);
    const int R1 = c1 >> 2, S1 = (c1 & 3) ^ ((R1 >> 1) & 3);
    const f16* ga0 = A + (size_t)(bm * 128 + R0) * KP + S0 * 8;
    const f16* ga1 = A + (size_t)(bm * 128 + R1) * KP + S1 * 8;
    const f16* gb0 = W + (size_t)(bn * 128 + R0) * KP + S0 * 8;
    const f16* gb1 = W + (size_t)(bn * 128 + R1) * KP + S1 * 8;

    // K-invariant swizzled LDS read offsets (f16 elem units)
    int aoff[4], boff[4];
#pragma unroll
    for (int m = 0; m < 4; ++m) {
        int ra = wr * 64 + m * 16 + lrow;
        aoff[m] = ra * 32 + ((lseg ^ ((ra >> 1) & 3)) * 8);
        int rb = wc * 64 + m * 16 + lrow;
        boff[m] = rb * 32 + ((lseg ^ ((rb >> 1) & 3)) * 8);
    }

    // prologue: stage K-step 0 into buf 0
    {
        const int kof = ks0 * 32;
        GLOAD16(ga0 + kof, &As[0][c0 * 8]);
        GLOAD16(ga1 + kof, &As[0][c1 * 8]);
        GLOAD16(gb0 + kof, &Bs[0][c0 * 8]);
        GLOAD16(gb1 + kof, &Bs[0][c1 * 8]);
    }
    __syncthreads();                       // drains vmcnt: buf0 ready

    int cur = 0;
    for (int t = 0; t < KS_PER_Z; ++t) {
        const int nxt = cur ^ 1;
        if (t + 1 < KS_PER_Z) {            // issue next-tile loads FIRST (overlap)
            const int kof = (ks0 + t + 1) * 32;
            GLOAD16(ga0 + kof, &As[nxt][c0 * 8]);
            GLOAD16(ga1 + kof, &As[nxt][c1 * 8]);
            GLOAD16(gb0 + kof, &Bs[nxt][c0 * 8]);
            GLOAD16(gb1 + kof, &Bs[nxt][c1 * 8]);
        }
        f16x8 af[4], bf[4];
#pragma unroll
        for (int m = 0; m < 4; ++m) af[m] = *(const f16x8*)&As[cur][aoff[m]];
#pragma unroll
        for (int n = 0; n < 4; ++n) bf[n] = *(const f16x8*)&Bs[cur][boff[n]];
#pragma unroll
        for (int m = 0; m < 4; ++m)
#pragma unroll
            for (int n = 0; n < 4; ++n)
                acc[m][n] = __builtin_amdgcn_mfma_f32_16x16x32_f16(af[m], bf[n], acc[m][n], 0, 0, 0);
        __syncthreads();                   // one barrier/K-step: drains stage, fences reads
        cur = nxt;
    }

    // epilogue: accumulate across z via fp32 atomics (C zero-initialized)
    const int orow0 = bm * 128 + wr * 64 + (lane >> 4) * 4;
    const int ocol0 = bn * 128 + wc * 64 + (lane & 15);
#pragma unroll
    for (int m = 0; m < 4; ++m)
#pragma unroll
        for (int n = 0; n < 4; ++n)
#pragma unroll
            for (int j = 0; j < 4; ++j)
                atomicAdd(&C[(size_t)(orow0 + m * 16 + j) * NB + ocol0 + n * 16], acc[m][n][j]);
}

// ---- fused: per-row top-8 (exact on fp32 keys) + f64 rotation refine + patches ----
// grid B_N, block 512 (8 waves; 1 candidate per wave)
__global__ __launch_bounds__(512)
void fused_sel(const float* __restrict__ x, const float* __restrict__ C,
               const float* __restrict__ wp, float* __restrict__ out) {
    __shared__ float xrow[KP];
    __shared__ unsigned long long keybuf[64];
    __shared__ int bins8s[8];
    __shared__ unsigned long long rk[8];
    const int row = blockIdx.x, tid = threadIdx.x;
    const int wv = tid >> 6, lane = tid & 63;

    if (tid < 60) xrow[2500 + tid] = 0.f;          // pad region
#pragma unroll
    for (int i = 0; i < 2; ++i) {
        int slot = tid + 512 * i;                  // float4 slots 0..624
        if (slot < 625)
            *reinterpret_cast<float4*>(&xrow[slot * 4]) =
                *reinterpret_cast<const float4*>(x + (size_t)row * ROWSTRIDE + slot * 4);
    }

    // power keys: thread covers bins {tid, tid+512, tid+1024}
    unsigned long long k3[3];
#pragma unroll
    for (int c = 0; c < 3; ++c) {
        int bin = tid + 512 * c;
        unsigned long long key = 0ULL;
        if (bin <= 1250) {
            float2 ri = *reinterpret_cast<const float2*>(&C[(size_t)row * NB + 2 * bin]);
            float p = ri.x * ri.x + ri.y * ri.y;
            key = ((unsigned long long)__float_as_uint(p) << 32) | (unsigned)(L_N - bin);
        }
        k3[c] = key;
    }
    // wave-local top-8 (no barriers)
#pragma unroll
    for (int r = 0; r < 8; ++r) {
        unsigned long long m = k3[0];
        m = (k3[1] > m) ? k3[1] : m;
        m = (k3[2] > m) ? k3[2] : m;
#pragma unroll
        for (int off = 32; off > 0; off >>= 1) {
            unsigned long long o = __shfl_xor(m, off, 64);
            m = (o > m) ? o : m;
        }
        if (k3[0] == m) k3[0] = 0ULL;
        if (k3[1] == m) k3[1] = 0ULL;
        if (k3[2] == m) k3[2] = 0ULL;
        if (lane == 0) keybuf[wv * 8 + r] = m;
    }
    __syncthreads();
    // merge 8x8 wave-top8s in wave 0
    if (wv == 0) {
        unsigned long long cur = keybuf[lane];
#pragma unroll
        for (int r = 0; r < 8; ++r) {
            unsigned long long m = cur;
#pragma unroll
            for (int off = 32; off > 0; off >>= 1) {
                unsigned long long o = __shfl_xor(m, off, 64);
                m = (o > m) ? o : m;
            }
            if (cur == m) cur = 0ULL;
            if (lane == 0) bins8s[r] = L_N - (int)(unsigned)(m & 0xffffffffULL);
        }
    }
    __syncthreads();

    // f64 refine of candidate wv: sincos seed + 40-step in-register rotation
    const int k = bins8s[wv];
    double c, s, cd, sd;
    {
        int ph0 = (k * lane) % L_N;
        int phd = (k * 64) % L_N;
        sincos((double)ph0 * RAD_PER_PH, &s, &c);
        sincos((double)phd * RAD_PER_PH, &sd, &cd);
    }
    double re = 0.0, im = 0.0;
#pragma unroll 4
    for (int i = 0; i < 40; ++i) {            // 40*64 == 2560 == KP exactly
        double xv = (double)xrow[lane + 64 * i];
        re += xv * c;
        im += xv * s;
        double cn = c * cd - s * sd;
        double sn = s * cd + c * sd;
        c = cn; s = sn;
    }
#pragma unroll
    for (int off = 32; off > 0; off >>= 1) {
        re += __shfl_xor(re, off, 64);
        im += __shfl_xor(im, off, 64);
    }
    if (lane == 0) {
        double p = re * re + im * im;
        unsigned long long pb = (unsigned long long)__double_as_longlong(p);
        // clear 11 low mantissa bits (rel 2^-41); low field: smaller k wins ties
        rk[wv] = (pb & ~2047ULL) | (unsigned long long)(1250 - k);
    }
    __syncthreads();

    if (tid < NPATCH) {
        unsigned long long q[8];
#pragma unroll
        for (int r = 0; r < 8; ++r) q[r] = rk[r];
        unsigned long long m1 = q[0];
#pragma unroll
        for (int r = 1; r < 8; ++r) m1 = (q[r] > m1) ? q[r] : m1;
#pragma unroll
        for (int r = 0; r < 8; ++r) if (q[r] == m1) q[r] = 0;
        unsigned long long m2 = q[0];
#pragma unroll
        for (int r = 1; r < 8; ++r) m2 = (q[r] > m2) ? q[r] : m2;
#pragma unroll
        for (int r = 0; r < 8; ++r) if (q[r] == m2) q[r] = 0;
        unsigned long long m3 = q[0];
#pragma unroll
        for (int r = 1; r < 8; ++r) m3 = (q[r] > m3) ? q[r] : m3;

        int kA = 1250 - (int)(m1 & 2047ULL);
        int kB = 1250 - (int)(m2 & 2047ULL);
        int kC = 1250 - (int)(m3 & 2047ULL);
        int multA = (kA == 0 || kA == 1250) ? 1 : 2;
        int multB = (kB == 0 || kB == 1250) ? 1 : 2;
        int sel0 = kA;
        int sel1 = (multA == 2 || multB == 2) ? kB : kC;

        int start = tid * PATCH;
        int cnt = 0;
        if (sel0 != 0) {
            int p = L_N / sel0;
            int fm = ((start + p - 1) / p) * p;
            if (fm < start + PATCH) ++cnt;
        }
        if (sel1 != 0) {
            int p = L_N / sel1;
            int fm = ((start + p - 1) / p) * p;
            if (fm < start + PATCH) ++cnt;
        }
        out[(size_t)row * NPATCH + tid] = 12.0f * wp[0] * (float)cnt;
    }
}

extern "C" void kernel_launch(void* const* d_in, const int* in_sizes, int n_in,
                              void* d_out, int out_size, void* d_ws, size_t ws_size,
                              hipStream_t stream) {
    const float* x = (const float*)d_in[0];
    const float* w = (const float*)d_in[1];
    float* out = (float*)d_out;
    char* ws = (char*)d_ws;

    f16* Xh = (f16*)(ws + OFF_XH);
    f16* W  = (f16*)(ws + OFF_W);
    float* C = (float*)(ws + OFF_C);

    prep<<<PB_TOT, 256, 0, stream>>>(x, Xh, W, (float4*)C);
    gemm_f16<<<dim3(8, 20, ZSPLIT), 256, 0, stream>>>(Xh, W, C);
    fused_sel<<<B_N, 512, 0, stream>>>(x, C, w, out);
}